// Round 6
// baseline (394.174 us; speedup 1.0000x reference)
//
#include <hip/hip_runtime.h>
#include <cstdint>

#pragma clang fp contract(off)

#define HH 248
#define WW 216
#define HW (HH*WW)          // 53568 cells (divisible by 4)
#define NROW (6*HW)         // 321408 rows per batch
#define BATCH 16
#define NPRE 100
#define MAXNUM 50
#define NB 2048             // slow-path sigmoid bucket space
#define CAP 2048
#define SBLK 53             // blocks per batch, 1024 cells each
#define K0 64               // per-block speculative key slots (exp ~14 used)
#define NSLOT (SBLK*K0)     // 3392
#define QMAX 14             // ceil(NSLOT/256)
#define PIF 3.14159274101257324f

// speculative cut in LOGIT domain: logit(0.96) = ln(24).
// Monotone sigmoid => candidate set {x >= XCUT} == {score >= 0.96}; ordering
// by logit bits == ordering by score bits. ~700 candidates/batch expected.
#define XCUT 3.17805383f
#define FBINS 92            // fine logit bins: (bits-x0)>>17, covers x up to ~8.2

// ws layout (bytes):
//  [0,    64)     doneCnt: u32 [BATCH]  (zeroed per-iteration by hipMemsetAsync)
//  [64,   3456)   cntB: u32 [BATCH][SBLK]  per-block candidate counts (uncapped)
//  [3584, 437760) keys: u64 [BATCH][SBLK][K0] per-block key segments
#define DONE_OFF 0
#define CNTB_OFF 64
#define KEYS_OFF 3584

__device__ __forceinline__ float sigmoidf_ref(float x) {
    if (x >= 0.0f) {
        return 1.0f / (1.0f + expf(-x));
    } else {
        float e = expf(x);
        return e / (1.0f + e);
    }
}

// slow-path monotone bucket of positive sigmoid-score bits (unchanged)
__device__ __forceinline__ unsigned bucket_of(unsigned bits) {
    unsigned b = (bits >= 0x3F000000u) ? (1024u + ((bits - 0x3F000000u) >> 13))
                                       : (bits >> 20);
    return (b > (unsigned)(NB - 1)) ? (unsigned)(NB - 1) : b;
}

// monotone fine bin of candidate logit bits; -1 for non-candidates/empty slots
__device__ __forceinline__ int lbin(unsigned bits, unsigned x0) {
    if (bits < x0) return -1;
    unsigned d = (bits - x0) >> 17;
    return (d > (unsigned)(FBINS - 1)) ? (FBINS - 1) : (int)d;
}

// ---- Fused kernel: phase A = streaming collect (no sigmoid, no histogram);
//      last-arriving block per batch proceeds to phase B = threshold + top-100
//      + decode + 3x NMS + top-50. Cross-block visibility: release fence +
//      device-scope atomic counter + acquire fence (decoupled-lookback idiom).
__global__ __launch_bounds__(256) void k_fused(
    const float* __restrict__ cls, const float* __restrict__ box,
    const float* __restrict__ dir, const float* __restrict__ anc,
    unsigned* __restrict__ doneCnt, unsigned* __restrict__ cntB,
    unsigned long long* __restrict__ keys,
    float* __restrict__ out) {
    int t = threadIdx.x, blk = blockIdx.x, b = blockIdx.y;   // 256 threads
    const unsigned x0 = __float_as_uint(XCUT);

    // ---------------- phase B shared state (also lcnt for phase A) ----------
    __shared__ unsigned long long keyS[CAP];           // 16 KB (slow path needs CAP)
    __shared__ int   selRow[NPRE];
    __shared__ float bb[NPRE][7];
    __shared__ float b2d[NPRE][4];
    __shared__ float areaS[NPRE];
    __shared__ float clsS[3][NPRE];
    __shared__ float svalS[3][NPRE];
    __shared__ int   ordS[3][NPRE];
    __shared__ int   rankS[3][NPRE];
    __shared__ float4 sbox[3][NPRE];                   // boxes in sorted order
    __shared__ float  sarea[3][NPRE];
    __shared__ unsigned keepInit[3][4];
    __shared__ unsigned long long maskS[3][NPRE][2];
    __shared__ unsigned long long keepBits[3][2];
    __shared__ float flatS[3*NPRE];
    __shared__ unsigned fh[FBINS];                     // candidate fine hist
    __shared__ unsigned fsuf[FBINS + 1];               // suffix sums
    __shared__ unsigned cntS[SBLK];
    __shared__ unsigned slowH[NB];                     // slow path only (8 KB)
    __shared__ int  tbS;
    __shared__ unsigned StbS;
    __shared__ int  safeS;
    __shared__ unsigned mcnt;
    __shared__ unsigned lcnt;
    __shared__ int  amLastS;

    // ---------------- phase A: streaming collect (logit domain) -------------
    if (t == 0) lcnt = 0;
    __syncthreads();

    unsigned long long* kseg = keys + (size_t)(b * SBLK + blk) * K0;
    int cell0 = blk * 1024 + t * 4;
    if (cell0 < HW) {               // HW%4==0 and cell0%4==0 -> full float4 in-bounds
        const float* p = cls + (size_t)b * 18 * HW;
        #pragma unroll
        for (int a = 0; a < 6; ++a) {
            float4 l0 = *(const float4*)(p + (size_t)(a*3+0)*HW + cell0);
            float4 l1 = *(const float4*)(p + (size_t)(a*3+1)*HW + cell0);
            float4 l2 = *(const float4*)(p + (size_t)(a*3+2)*HW + cell0);
            float m0 = fmaxf(l0.x, fmaxf(l1.x, l2.x));
            float m1 = fmaxf(l0.y, fmaxf(l1.y, l2.y));
            float m2 = fmaxf(l0.z, fmaxf(l1.z, l2.z));
            float m3 = fmaxf(l0.w, fmaxf(l1.w, l2.w));
            if (m0 >= XCUT) {
                unsigned pos = atomicAdd(&lcnt, 1u);
                if (pos < (unsigned)K0)
                    kseg[pos] = ((unsigned long long)__float_as_uint(m0) << 32) |
                                (unsigned long long)(0xFFFFFFFFu - (unsigned)((cell0+0)*6 + a));
            }
            if (m1 >= XCUT) {
                unsigned pos = atomicAdd(&lcnt, 1u);
                if (pos < (unsigned)K0)
                    kseg[pos] = ((unsigned long long)__float_as_uint(m1) << 32) |
                                (unsigned long long)(0xFFFFFFFFu - (unsigned)((cell0+1)*6 + a));
            }
            if (m2 >= XCUT) {
                unsigned pos = atomicAdd(&lcnt, 1u);
                if (pos < (unsigned)K0)
                    kseg[pos] = ((unsigned long long)__float_as_uint(m2) << 32) |
                                (unsigned long long)(0xFFFFFFFFu - (unsigned)((cell0+2)*6 + a));
            }
            if (m3 >= XCUT) {
                unsigned pos = atomicAdd(&lcnt, 1u);
                if (pos < (unsigned)K0)
                    kseg[pos] = ((unsigned long long)__float_as_uint(m3) << 32) |
                                (unsigned long long)(0xFFFFFFFFu - (unsigned)((cell0+3)*6 + a));
            }
        }
    }
    __syncthreads();
    if (t == 0) cntB[b * SBLK + blk] = lcnt;   // uncapped (overflow detect)

    // release: make this block's keys+cnt visible device-wide, then signal
    __threadfence();
    if (t == 0) {
        unsigned done = atomicAdd(&doneCnt[b], 1u);
        amLastS = (done == (unsigned)(SBLK - 1)) ? 1 : 0;
    }
    __syncthreads();
    if (!amLastS) return;
    __threadfence();   // acquire: invalidate caches; subsequent loads are fresh

    // ---------------- phase B: per-batch final (last block only) ------------
    if (t == 0) { tbS = -1; StbS = 0; mcnt = 0; }
    if (t < FBINS) fh[t] = 0;
    if (t == FBINS) fsuf[FBINS] = 0;
    if (t < SBLK) cntS[t] = cntB[b * SBLK + t];
    __syncthreads();

    // issue all speculative key loads into registers (independent)
    unsigned long long kq[QMAX];
    #pragma unroll
    for (int q = 0; q < QMAX; ++q) {
        unsigned long long kk = 0ULL;
        int s = t + q * 256;
        if (s < NSLOT) {
            int k = s >> 6, i = s & 63;
            if ((unsigned)i < cntS[k])
                kk = keys[(size_t)(b * SBLK + k) * K0 + i];
        }
        kq[q] = kk;
    }

    // fine histogram of candidate logit bits (empty slots -> bits 0 -> skipped)
    #pragma unroll
    for (int q = 0; q < QMAX; ++q) {
        int bk = lbin((unsigned)(kq[q] >> 32), x0);
        if (bk >= 0) atomicAdd(&fh[bk], 1u);
    }
    __syncthreads();

    // suffix sums over 92 bins (parallel, 4-wide)
    if (t < FBINS) {
        unsigned s = 0;
        int j = t;
        for (; j + 3 < FBINS; j += 4)
            s += fh[j] + fh[j+1] + fh[j+2] + fh[j+3];
        for (; j < FBINS; ++j) s += fh[j];
        fsuf[t] = s;
    }
    __syncthreads();
    if (t < FBINS) {
        unsigned S = fsuf[t], Sn = fsuf[t + 1];
        if (S >= (unsigned)NPRE && Sn < (unsigned)NPRE) {   // exactly one writer
            tbS = t;
            StbS = S;                                       // = count(bin >= tb)
        }
    }
    __syncthreads();

    // safety: >=100 candidates, no segment overflow, filtered set fits keyS
    if (t < 64) {
        unsigned c = (t < SBLK) ? cntS[t] : 0u;
        unsigned long long ov = __ballot(c > (unsigned)K0);
        if (t == 0)
            safeS = (tbS >= 0) && (ov == 0ULL) && (StbS <= (unsigned)CAP) ? 1 : 0;
    }
    __syncthreads();

    int M;
    if (safeS) {
        int tbin = tbS;
        // filter register-held keys by exact fine bin; ~100-130 winners
        #pragma unroll
        for (int q = 0; q < QMAX; ++q) {
            unsigned long long kk = kq[q];
            if (lbin((unsigned)(kk >> 32), x0) >= tbin) {
                unsigned pos = atomicAdd(&mcnt, 1u);
                keyS[pos] = kk;
            }
        }
        __syncthreads();
        M = (int)mcnt;
    } else {
        // slow path (never taken on bench data): exact sigmoid-domain rebuild
        for (int i = t; i < NB; i += 256) slowH[i] = 0;
        __syncthreads();
        const float* p = cls + (size_t)b * 18 * HW;
        for (int cell = t; cell < HW; cell += 256) {
            for (int a = 0; a < 6; ++a) {
                float v0 = p[(size_t)(a*3+0)*HW + cell];
                float v1 = p[(size_t)(a*3+1)*HW + cell];
                float v2 = p[(size_t)(a*3+2)*HW + cell];
                unsigned bits = __float_as_uint(sigmoidf_ref(fmaxf(v0, fmaxf(v1, v2))));
                atomicAdd(&slowH[bucket_of(bits)], 1u);
            }
        }
        __syncthreads();
        if (t == 0) {
            unsigned cum = 0;
            int r = 0;
            for (int j = NB - 1; j >= 0; --j) {
                cum += slowH[j];
                if (cum >= (unsigned)NPRE) { r = j; break; }
            }
            tbS = r;
        }
        __syncthreads();
        int tb = tbS;
        for (int cell = t; cell < HW; cell += 256) {
            for (int a = 0; a < 6; ++a) {
                float v0 = p[(size_t)(a*3+0)*HW + cell];
                float v1 = p[(size_t)(a*3+1)*HW + cell];
                float v2 = p[(size_t)(a*3+2)*HW + cell];
                unsigned bits = __float_as_uint(sigmoidf_ref(fmaxf(v0, fmaxf(v1, v2))));
                if (bucket_of(bits) >= (unsigned)tb) {
                    unsigned pos = atomicAdd(&mcnt, 1u);
                    if (pos < (unsigned)CAP)
                        keyS[pos] = ((unsigned long long)bits << 32) |
                                    (unsigned long long)(0xFFFFFFFFu - (unsigned)(cell*6 + a));
                }
            }
        }
        __syncthreads();
        M = (mcnt < (unsigned)CAP) ? (int)mcnt : CAP;
    }
    __syncthreads();

    // exact top-100: keys unique -> ranks unique (ordering identical to
    // sigmoid-domain: monotone bijection on the score field)
    for (int i = t; i < M; i += 256) {
        unsigned long long k = keyS[i];
        int r = 0;
        int j = 0;
        for (; j + 3 < M; j += 4) {
            unsigned long long a0 = keyS[j+0], a1 = keyS[j+1];
            unsigned long long a2 = keyS[j+2], a3 = keyS[j+3];
            r += (int)(a0 > k) + (int)(a1 > k) + (int)(a2 > k) + (int)(a3 > k);
        }
        for (; j < M; ++j) r += (int)(keyS[j] > k);
        if (r < NPRE) selRow[r] = (int)(0xFFFFFFFFu - (unsigned)(k & 0xFFFFFFFFull));
    }
    __syncthreads();

    // decode the 100 selected rows
    if (t < NPRE) {
        int row = selRow[t];
        int a = row % 6;
        int cell = row / 6;
        const float* cb = cls + (size_t)b * 18 * HW + cell;
        clsS[0][t] = sigmoidf_ref(cb[(size_t)(a*3+0)*HW]);
        clsS[1][t] = sigmoidf_ref(cb[(size_t)(a*3+1)*HW]);
        clsS[2][t] = sigmoidf_ref(cb[(size_t)(a*3+2)*HW]);
        const float* db = dir + (size_t)b * 12 * HW + cell;
        float d0 = db[(size_t)(a*2+0)*HW];
        float d1 = db[(size_t)(a*2+1)*HW];
        int dircls = (d1 > d0) ? 1 : 0;
        const float* pb = box + (size_t)b * 42 * HW + cell;
        float dx = pb[(size_t)(a*7+0)*HW], dy = pb[(size_t)(a*7+1)*HW], dz = pb[(size_t)(a*7+2)*HW];
        float dw = pb[(size_t)(a*7+3)*HW], dl = pb[(size_t)(a*7+4)*HW], dh = pb[(size_t)(a*7+5)*HW];
        float dr = pb[(size_t)(a*7+6)*HW];
        const float* ab = anc + (size_t)row * 7;
        float xa = ab[0], ya = ab[1], za = ab[2];
        float wa = ab[3], la = ab[4], ha = ab[5], ra = ab[6];
        float da = sqrtf(wa*wa + la*la);
        float x = dx*da + xa;
        float y = dy*da + ya;
        float z = dz*ha + za + ha*0.5f;
        float wv = wa*expf(dw);
        float lv = la*expf(dl);
        float hv = ha*expf(dh);
        z = z - hv*0.5f;
        float th0 = ra + dr;
        float lim = th0 - floorf(th0/PIF + 1.0f)*PIF;
        float theta = lim + (1.0f - (float)dircls)*PIF;
        bb[t][0]=x; bb[t][1]=y; bb[t][2]=z; bb[t][3]=wv; bb[t][4]=lv; bb[t][5]=hv; bb[t][6]=theta;
        b2d[t][0] = x - wv*0.5f;
        b2d[t][1] = y - lv*0.5f;
        b2d[t][2] = x + wv*0.5f;
        b2d[t][3] = y + lv*0.5f;
        areaS[t] = (b2d[t][2]-b2d[t][0]) * (b2d[t][3]-b2d[t][1]);
    }
    if (t < 12) keepInit[t/4][t%4] = 0u;
    __syncthreads();

    // masked scores
    for (int w = t; w < 3*NPRE; w += 256) {
        int c = w / NPRE, p = w % NPRE;
        float sc = clsS[c][p];
        svalS[c][p] = (sc > 0.1f) ? sc : -INFINITY;
    }
    __syncthreads();

    // stable descending rank per class (ties -> lower index first), 4-wide
    for (int w = t; w < 3*NPRE; w += 256) {
        int c = w / NPRE, p = w % NPRE;
        float v = svalS[c][p];
        int r = 0;
        for (int j0 = 0; j0 < NPRE; j0 += 4) {
            float v0 = svalS[c][j0+0], v1 = svalS[c][j0+1];
            float v2 = svalS[c][j0+2], v3 = svalS[c][j0+3];
            r += (int)(v0 > v || (v0 == v && (j0+0) < p));
            r += (int)(v1 > v || (v1 == v && (j0+1) < p));
            r += (int)(v2 > v || (v2 == v && (j0+2) < p));
            r += (int)(v3 > v || (v3 == v && (j0+3) < p));
        }
        ordS[c][r] = p;
        rankS[c][p] = r;
        if (v != -INFINITY) atomicOr(&keepInit[c][r >> 5], 1u << (r & 31));
    }
    __syncthreads();

    // stage boxes in sorted order so the NMS inner loop is single-level LDS
    for (int w = t; w < 3*NPRE; w += 256) {
        int c = w / NPRE, i = w % NPRE;
        int pi = ordS[c][i];
        sbox[c][i] = make_float4(b2d[pi][0], b2d[pi][1], b2d[pi][2], b2d[pi][3]);
        sarea[c][i] = areaS[pi];
    }
    __syncthreads();

    // pairwise suppression masks in sorted space (j > i, iou > thr)
    for (int w = t; w < 3*NPRE; w += 256) {
        int c = w / NPRE, i = w % NPRE;
        float4 bi = sbox[c][i];
        float ai = sarea[c][i];
        unsigned long long m0 = 0ULL, m1 = 0ULL;
        #pragma unroll 2
        for (int j = i + 1; j < NPRE; ++j) {
            float4 bj = sbox[c][j];
            float x1 = fmaxf(bi.x, bj.x);
            float y1 = fmaxf(bi.y, bj.y);
            float x2 = fminf(bi.z, bj.z);
            float y2 = fminf(bi.w, bj.w);
            float inter = fmaxf(x2 - x1, 0.0f) * fmaxf(y2 - y1, 0.0f);
            float iou = inter / (ai + sarea[c][j] - inter + 1e-8f);
            unsigned long long hit = (iou > 0.01f) ? 1ULL : 0ULL;
            if (j < 64) m0 |= hit << j;
            else        m1 |= hit << (j - 64);
        }
        maskS[c][i][0] = m0;
        maskS[c][i][1] = m1;
    }
    __syncthreads();

    // greedy walk, one lane per class, ctz-skip over surviving bits only
    if (t < 3) {
        int c = t;
        unsigned long long k0 = (unsigned long long)keepInit[c][0] |
                                ((unsigned long long)keepInit[c][1] << 32);
        unsigned long long k1 = (unsigned long long)keepInit[c][2] |
                                ((unsigned long long)keepInit[c][3] << 32);
        unsigned long long todo = k0;
        while (todo) {
            int i = __builtin_ctzll(todo);
            unsigned long long m0 = maskS[c][i][0];
            unsigned long long m1 = maskS[c][i][1];
            k0 &= ~m0;
            k1 &= ~m1;
            todo = (todo & (todo - 1)) & ~m0;   // drop bit i + suppressed
        }
        todo = k1;
        while (todo) {
            int i = __builtin_ctzll(todo);      // global index 64+i
            unsigned long long m1 = maskS[c][64 + i][1];  // [64+i][0] is empty
            k1 &= ~m1;
            todo = (todo & (todo - 1)) & ~m1;
        }
        keepBits[c][0] = k0;
        keepBits[c][1] = k1;
    }
    __syncthreads();

    // flat masked score array (keep already includes validity)
    for (int w = t; w < 3*NPRE; w += 256) {
        int c = w / NPRE, p = w % NPRE;
        int r = rankS[c][p];
        unsigned long long bit = (r < 64) ? (keepBits[c][0] >> r) : (keepBits[c][1] >> (r - 64));
        flatS[w] = (bit & 1ULL) ? clsS[c][p] : -1.0f;
    }
    __syncthreads();

    // stable top-50 over 300 entries, 4-wide; ranks unique
    for (int i = t; i < 3*NPRE; i += 256) {
        float vi = flatS[i];
        int r2 = 0;
        for (int j0 = 0; j0 < 3*NPRE; j0 += 4) {
            float v0 = flatS[j0+0], v1 = flatS[j0+1];
            float v2 = flatS[j0+2], v3 = flatS[j0+3];
            r2 += (int)(v0 > vi || (v0 == vi && (j0+0) < i));
            r2 += (int)(v1 > vi || (v1 == vi && (j0+1) < i));
            r2 += (int)(v2 > vi || (v2 == vi && (j0+2) < i));
            r2 += (int)(v3 > vi || (v3 == vi && (j0+3) < i));
        }
        if (r2 < MAXNUM) {
            int p = i % NPRE;
            int lab = i / NPRE;
            int o = b * MAXNUM + r2;
            float* ob = out + (size_t)o * 7;
            for (int j = 0; j < 7; ++j) ob[j] = bb[p][j];
            out[BATCH*MAXNUM*7 + o] = (float)lab;
            out[BATCH*MAXNUM*8 + o] = vi;
            out[BATCH*MAXNUM*9 + o] = (vi > 0.0f) ? 1.0f : 0.0f;
        }
    }
}

extern "C" void kernel_launch(void* const* d_in, const int* in_sizes, int n_in,
                              void* d_out, int out_size, void* d_ws, size_t ws_size,
                              hipStream_t stream) {
    const float* cls = (const float*)d_in[0];
    const float* box = (const float*)d_in[1];
    const float* dir = (const float*)d_in[2];
    const float* anc = (const float*)d_in[3];
    float* out = (float*)d_out;
    char* ws = (char*)d_ws;

    unsigned* doneCnt = (unsigned*)(ws + DONE_OFF);
    unsigned* cntB = (unsigned*)(ws + CNTB_OFF);
    unsigned long long* keys = (unsigned long long*)(ws + KEYS_OFF);

    // zero the 16 per-batch done counters (workspace is poisoned per iteration)
    hipMemsetAsync(doneCnt, 0, 64, stream);

    dim3 g(SBLK, BATCH);
    k_fused<<<g, 256, 0, stream>>>(cls, box, dir, anc, doneCnt, cntB, keys, out);
}

// Round 8
// 292.275 us; speedup vs baseline: 1.3486x; 1.3486x over previous
//
#include <hip/hip_runtime.h>
#include <cstdint>

#pragma clang fp contract(off)

#define HH 248
#define WW 216
#define HW (HH*WW)          // 53568 cells (divisible by 4)
#define NROW (6*HW)         // 321408 rows per batch
#define BATCH 16
#define NPRE 100
#define MAXNUM 50
#define NB 2048             // slow-path sigmoid bucket space
#define CAP 2048
#define SBLK 53             // blocks per batch, 1024 cells each
#define K0 64               // per-block speculative key slots (exp ~14 used)
#define NSLOT (SBLK*K0)     // 3392
#define QMAX 14             // ceil(NSLOT/256)
#define PIF 3.14159274101257324f

// speculative cut in LOGIT domain: logit(0.96) = ln(24).
// Monotone sigmoid => candidate set {x >= XCUT} == {score >= 0.96}; ordering
// by logit bits == ordering by score bits (both positive-float monotone).
#define XCUT 3.17805383f
#define FBINS 92            // fine logit bins: (bits-x0)>>17, covers x up to ~8.2

// ws layout (bytes):
//  [0,    3392)   cntB: u32 [BATCH][SBLK]  per-block candidate counts (uncapped)
//  [3584, 437760) keys: u64 [BATCH][SBLK][K0] per-block key segments
#define CNTB_OFF 0
#define KEYS_OFF 3584

__device__ __forceinline__ float sigmoidf_ref(float x) {
    if (x >= 0.0f) {
        return 1.0f / (1.0f + expf(-x));
    } else {
        float e = expf(x);
        return e / (1.0f + e);
    }
}

// slow-path monotone bucket of positive sigmoid-score bits
__device__ __forceinline__ unsigned bucket_of(unsigned bits) {
    unsigned b = (bits >= 0x3F000000u) ? (1024u + ((bits - 0x3F000000u) >> 13))
                                       : (bits >> 20);
    return (b > (unsigned)(NB - 1)) ? (unsigned)(NB - 1) : b;
}

// monotone fine bin of candidate logit bits; -1 for non-candidates/empty slots
__device__ __forceinline__ int lbin(unsigned bits, unsigned x0) {
    if (bits < x0) return -1;
    unsigned d = (bits - x0) >> 17;
    return (d > (unsigned)(FBINS - 1)) ? (FBINS - 1) : (int)d;
}

// ---- Pass 1: pure streaming collect in LOGIT domain — float4 loads, fmax,
// compare, rare key emit. No sigmoid, no histogram, no fences (the dispatch
// boundary orders pass 1 before pass 2 for free; R6 showed per-block
// __threadfence on gfx950 = L2-writeback storm, +100us).
__global__ __launch_bounds__(256) void k_score(const float* __restrict__ cls,
                                               unsigned* __restrict__ cntB,
                                               unsigned long long* __restrict__ keys) {
    int t = threadIdx.x, blk = blockIdx.x, b = blockIdx.y;
    __shared__ unsigned lcnt;
    if (t == 0) lcnt = 0;
    __syncthreads();

    unsigned long long* kseg = keys + (size_t)(b * SBLK + blk) * K0;
    int cell0 = blk * 1024 + t * 4;
    if (cell0 < HW) {               // HW%4==0 and cell0%4==0 -> full float4 in-bounds
        const float* p = cls + (size_t)b * 18 * HW;
        #pragma unroll
        for (int a = 0; a < 6; ++a) {
            float4 l0 = *(const float4*)(p + (size_t)(a*3+0)*HW + cell0);
            float4 l1 = *(const float4*)(p + (size_t)(a*3+1)*HW + cell0);
            float4 l2 = *(const float4*)(p + (size_t)(a*3+2)*HW + cell0);
            float m0 = fmaxf(l0.x, fmaxf(l1.x, l2.x));
            float m1 = fmaxf(l0.y, fmaxf(l1.y, l2.y));
            float m2 = fmaxf(l0.z, fmaxf(l1.z, l2.z));
            float m3 = fmaxf(l0.w, fmaxf(l1.w, l2.w));
            if (m0 >= XCUT) {
                unsigned pos = atomicAdd(&lcnt, 1u);
                if (pos < (unsigned)K0)
                    kseg[pos] = ((unsigned long long)__float_as_uint(m0) << 32) |
                                (unsigned long long)(0xFFFFFFFFu - (unsigned)((cell0+0)*6 + a));
            }
            if (m1 >= XCUT) {
                unsigned pos = atomicAdd(&lcnt, 1u);
                if (pos < (unsigned)K0)
                    kseg[pos] = ((unsigned long long)__float_as_uint(m1) << 32) |
                                (unsigned long long)(0xFFFFFFFFu - (unsigned)((cell0+1)*6 + a));
            }
            if (m2 >= XCUT) {
                unsigned pos = atomicAdd(&lcnt, 1u);
                if (pos < (unsigned)K0)
                    kseg[pos] = ((unsigned long long)__float_as_uint(m2) << 32) |
                                (unsigned long long)(0xFFFFFFFFu - (unsigned)((cell0+2)*6 + a));
            }
            if (m3 >= XCUT) {
                unsigned pos = atomicAdd(&lcnt, 1u);
                if (pos < (unsigned)K0)
                    kseg[pos] = ((unsigned long long)__float_as_uint(m3) << 32) |
                                (unsigned long long)(0xFFFFFFFFu - (unsigned)((cell0+3)*6 + a));
            }
        }
    }
    __syncthreads();
    if (t == 0) cntB[b * SBLK + blk] = lcnt;   // uncapped (overflow detect)
}

// ---- Pass 2: candidate-derived threshold (92-bin logit hist from registers),
//      ballot safety, reg filter, then top-100/decode/NMS/top-50.
//      Slow path: exact sigmoid-domain rebuild from cls (never taken on bench).
__global__ __launch_bounds__(256) void k_final(
    const float* __restrict__ cls, const float* __restrict__ box,
    const float* __restrict__ dir, const float* __restrict__ anc,
    const unsigned* __restrict__ cntB, const unsigned long long* __restrict__ keys,
    float* __restrict__ out) {
    int b = blockIdx.x, t = threadIdx.x;   // 256 threads
    const unsigned x0 = __float_as_uint(XCUT);

    __shared__ unsigned long long keyS[CAP];           // 16 KB (slow path needs CAP)
    __shared__ int   selRow[NPRE];
    __shared__ float bb[NPRE][7];
    __shared__ float b2d[NPRE][4];
    __shared__ float areaS[NPRE];
    __shared__ float clsS[3][NPRE];
    __shared__ float svalS[3][NPRE];
    __shared__ int   ordS[3][NPRE];
    __shared__ int   rankS[3][NPRE];
    __shared__ float4 sbox[3][NPRE];                   // boxes in sorted order
    __shared__ float  sarea[3][NPRE];
    __shared__ unsigned keepInit[3][4];
    __shared__ unsigned long long maskS[3][NPRE][2];
    __shared__ unsigned long long keepBits[3][2];
    __shared__ float flatS[3*NPRE];
    __shared__ unsigned fh[FBINS];                     // candidate fine hist
    __shared__ unsigned fsuf[FBINS + 1];               // suffix sums
    __shared__ unsigned cntS[SBLK];
    __shared__ unsigned slowH[NB];                     // slow path only (8 KB)
    __shared__ int  tbS;
    __shared__ unsigned StbS;
    __shared__ int  safeS;
    __shared__ unsigned mcnt;

    if (t == 0) { tbS = -1; StbS = 0; mcnt = 0; }
    if (t < FBINS) fh[t] = 0;
    if (t == FBINS) fsuf[FBINS] = 0;
    if (t < SBLK) cntS[t] = cntB[b * SBLK + t];
    __syncthreads();

    // issue all speculative key loads into registers (independent)
    unsigned long long kq[QMAX];
    #pragma unroll
    for (int q = 0; q < QMAX; ++q) {
        unsigned long long kk = 0ULL;
        int s = t + q * 256;
        if (s < NSLOT) {
            int k = s >> 6, i = s & 63;
            if ((unsigned)i < cntS[k])
                kk = keys[(size_t)(b * SBLK + k) * K0 + i];
        }
        kq[q] = kk;
    }

    // fine histogram of candidate logit bits (empty slots -> bits 0 -> skipped)
    #pragma unroll
    for (int q = 0; q < QMAX; ++q) {
        int bk = lbin((unsigned)(kq[q] >> 32), x0);
        if (bk >= 0) atomicAdd(&fh[bk], 1u);
    }
    __syncthreads();

    // suffix sums over 92 bins (parallel, 4-wide)
    if (t < FBINS) {
        unsigned s = 0;
        int j = t;
        for (; j + 3 < FBINS; j += 4)
            s += fh[j] + fh[j+1] + fh[j+2] + fh[j+3];
        for (; j < FBINS; ++j) s += fh[j];
        fsuf[t] = s;
    }
    __syncthreads();
    if (t < FBINS) {
        unsigned S = fsuf[t], Sn = fsuf[t + 1];
        if (S >= (unsigned)NPRE && Sn < (unsigned)NPRE) {   // exactly one writer
            tbS = t;
            StbS = S;                                       // = count(bin >= tb)
        }
    }
    __syncthreads();

    // safety: >=100 candidates, no segment overflow, filtered set fits keyS
    if (t < 64) {
        unsigned c = (t < SBLK) ? cntS[t] : 0u;
        unsigned long long ov = __ballot(c > (unsigned)K0);
        if (t == 0)
            safeS = (tbS >= 0) && (ov == 0ULL) && (StbS <= (unsigned)CAP) ? 1 : 0;
    }
    __syncthreads();

    int M;
    if (safeS) {
        int tbin = tbS;
        // filter register-held keys by exact fine bin; ~100-130 winners
        #pragma unroll
        for (int q = 0; q < QMAX; ++q) {
            unsigned long long kk = kq[q];
            if (lbin((unsigned)(kk >> 32), x0) >= tbin) {
                unsigned pos = atomicAdd(&mcnt, 1u);
                keyS[pos] = kk;
            }
        }
        __syncthreads();
        M = (int)mcnt;
    } else {
        // slow path (never taken on bench data): exact sigmoid-domain rebuild
        for (int i = t; i < NB; i += 256) slowH[i] = 0;
        __syncthreads();
        const float* p = cls + (size_t)b * 18 * HW;
        for (int cell = t; cell < HW; cell += 256) {
            for (int a = 0; a < 6; ++a) {
                float v0 = p[(size_t)(a*3+0)*HW + cell];
                float v1 = p[(size_t)(a*3+1)*HW + cell];
                float v2 = p[(size_t)(a*3+2)*HW + cell];
                unsigned bits = __float_as_uint(sigmoidf_ref(fmaxf(v0, fmaxf(v1, v2))));
                atomicAdd(&slowH[bucket_of(bits)], 1u);
            }
        }
        __syncthreads();
        if (t == 0) {
            unsigned cum = 0;
            int r = 0;
            for (int j = NB - 1; j >= 0; --j) {
                cum += slowH[j];
                if (cum >= (unsigned)NPRE) { r = j; break; }
            }
            tbS = r;
        }
        __syncthreads();
        int tb = tbS;
        for (int cell = t; cell < HW; cell += 256) {
            for (int a = 0; a < 6; ++a) {
                float v0 = p[(size_t)(a*3+0)*HW + cell];
                float v1 = p[(size_t)(a*3+1)*HW + cell];
                float v2 = p[(size_t)(a*3+2)*HW + cell];
                unsigned bits = __float_as_uint(sigmoidf_ref(fmaxf(v0, fmaxf(v1, v2))));
                if (bucket_of(bits) >= (unsigned)tb) {
                    unsigned pos = atomicAdd(&mcnt, 1u);
                    if (pos < (unsigned)CAP)
                        keyS[pos] = ((unsigned long long)bits << 32) |
                                    (unsigned long long)(0xFFFFFFFFu - (unsigned)(cell*6 + a));
                }
            }
        }
        __syncthreads();
        M = (mcnt < (unsigned)CAP) ? (int)mcnt : CAP;
    }
    __syncthreads();

    // exact top-100: keys unique -> ranks unique (logit-bit order == score order)
    for (int i = t; i < M; i += 256) {
        unsigned long long k = keyS[i];
        int r = 0;
        int j = 0;
        for (; j + 3 < M; j += 4) {
            unsigned long long a0 = keyS[j+0], a1 = keyS[j+1];
            unsigned long long a2 = keyS[j+2], a3 = keyS[j+3];
            r += (int)(a0 > k) + (int)(a1 > k) + (int)(a2 > k) + (int)(a3 > k);
        }
        for (; j < M; ++j) r += (int)(keyS[j] > k);
        if (r < NPRE) selRow[r] = (int)(0xFFFFFFFFu - (unsigned)(k & 0xFFFFFFFFull));
    }
    __syncthreads();

    // decode the 100 selected rows (exact sigmoid here, 300 expf total)
    if (t < NPRE) {
        int row = selRow[t];
        int a = row % 6;
        int cell = row / 6;
        const float* cb = cls + (size_t)b * 18 * HW + cell;
        clsS[0][t] = sigmoidf_ref(cb[(size_t)(a*3+0)*HW]);
        clsS[1][t] = sigmoidf_ref(cb[(size_t)(a*3+1)*HW]);
        clsS[2][t] = sigmoidf_ref(cb[(size_t)(a*3+2)*HW]);
        const float* db = dir + (size_t)b * 12 * HW + cell;
        float d0 = db[(size_t)(a*2+0)*HW];
        float d1 = db[(size_t)(a*2+1)*HW];
        int dircls = (d1 > d0) ? 1 : 0;
        const float* pb = box + (size_t)b * 42 * HW + cell;
        float dx = pb[(size_t)(a*7+0)*HW], dy = pb[(size_t)(a*7+1)*HW], dz = pb[(size_t)(a*7+2)*HW];
        float dw = pb[(size_t)(a*7+3)*HW], dl = pb[(size_t)(a*7+4)*HW], dh = pb[(size_t)(a*7+5)*HW];
        float dr = pb[(size_t)(a*7+6)*HW];
        const float* ab = anc + (size_t)row * 7;
        float xa = ab[0], ya = ab[1], za = ab[2];
        float wa = ab[3], la = ab[4], ha = ab[5], ra = ab[6];
        float da = sqrtf(wa*wa + la*la);
        float x = dx*da + xa;
        float y = dy*da + ya;
        float z = dz*ha + za + ha*0.5f;
        float wv = wa*expf(dw);
        float lv = la*expf(dl);
        float hv = ha*expf(dh);
        z = z - hv*0.5f;
        float th0 = ra + dr;
        float lim = th0 - floorf(th0/PIF + 1.0f)*PIF;
        float theta = lim + (1.0f - (float)dircls)*PIF;
        bb[t][0]=x; bb[t][1]=y; bb[t][2]=z; bb[t][3]=wv; bb[t][4]=lv; bb[t][5]=hv; bb[t][6]=theta;
        b2d[t][0] = x - wv*0.5f;
        b2d[t][1] = y - lv*0.5f;
        b2d[t][2] = x + wv*0.5f;
        b2d[t][3] = y + lv*0.5f;
        areaS[t] = (b2d[t][2]-b2d[t][0]) * (b2d[t][3]-b2d[t][1]);
    }
    if (t < 12) keepInit[t/4][t%4] = 0u;
    __syncthreads();

    // masked scores
    for (int w = t; w < 3*NPRE; w += 256) {
        int c = w / NPRE, p = w % NPRE;
        float sc = clsS[c][p];
        svalS[c][p] = (sc > 0.1f) ? sc : -INFINITY;
    }
    __syncthreads();

    // stable descending rank per class (ties -> lower index first), 4-wide
    for (int w = t; w < 3*NPRE; w += 256) {
        int c = w / NPRE, p = w % NPRE;
        float v = svalS[c][p];
        int r = 0;
        for (int j0 = 0; j0 < NPRE; j0 += 4) {
            float v0 = svalS[c][j0+0], v1 = svalS[c][j0+1];
            float v2 = svalS[c][j0+2], v3 = svalS[c][j0+3];
            r += (int)(v0 > v || (v0 == v && (j0+0) < p));
            r += (int)(v1 > v || (v1 == v && (j0+1) < p));
            r += (int)(v2 > v || (v2 == v && (j0+2) < p));
            r += (int)(v3 > v || (v3 == v && (j0+3) < p));
        }
        ordS[c][r] = p;
        rankS[c][p] = r;
        if (v != -INFINITY) atomicOr(&keepInit[c][r >> 5], 1u << (r & 31));
    }
    __syncthreads();

    // stage boxes in sorted order so the NMS inner loop is single-level LDS
    for (int w = t; w < 3*NPRE; w += 256) {
        int c = w / NPRE, i = w % NPRE;
        int pi = ordS[c][i];
        sbox[c][i] = make_float4(b2d[pi][0], b2d[pi][1], b2d[pi][2], b2d[pi][3]);
        sarea[c][i] = areaS[pi];
    }
    __syncthreads();

    // pairwise suppression masks in sorted space (j > i, iou > thr)
    for (int w = t; w < 3*NPRE; w += 256) {
        int c = w / NPRE, i = w % NPRE;
        float4 bi = sbox[c][i];
        float ai = sarea[c][i];
        unsigned long long m0 = 0ULL, m1 = 0ULL;
        #pragma unroll 2
        for (int j = i + 1; j < NPRE; ++j) {
            float4 bj = sbox[c][j];
            float x1 = fmaxf(bi.x, bj.x);
            float y1 = fmaxf(bi.y, bj.y);
            float x2 = fminf(bi.z, bj.z);
            float y2 = fminf(bi.w, bj.w);
            float inter = fmaxf(x2 - x1, 0.0f) * fmaxf(y2 - y1, 0.0f);
            float iou = inter / (ai + sarea[c][j] - inter + 1e-8f);
            unsigned long long hit = (iou > 0.01f) ? 1ULL : 0ULL;
            if (j < 64) m0 |= hit << j;
            else        m1 |= hit << (j - 64);
        }
        maskS[c][i][0] = m0;
        maskS[c][i][1] = m1;
    }
    __syncthreads();

    // greedy walk, one lane per class, ctz-skip over surviving bits only
    if (t < 3) {
        int c = t;
        unsigned long long k0 = (unsigned long long)keepInit[c][0] |
                                ((unsigned long long)keepInit[c][1] << 32);
        unsigned long long k1 = (unsigned long long)keepInit[c][2] |
                                ((unsigned long long)keepInit[c][3] << 32);
        unsigned long long todo = k0;
        while (todo) {
            int i = __builtin_ctzll(todo);
            unsigned long long m0 = maskS[c][i][0];
            unsigned long long m1 = maskS[c][i][1];
            k0 &= ~m0;
            k1 &= ~m1;
            todo = (todo & (todo - 1)) & ~m0;   // drop bit i + suppressed
        }
        todo = k1;
        while (todo) {
            int i = __builtin_ctzll(todo);      // global index 64+i
            unsigned long long m1 = maskS[c][64 + i][1];  // [64+i][0] is empty
            k1 &= ~m1;
            todo = (todo & (todo - 1)) & ~m1;
        }
        keepBits[c][0] = k0;
        keepBits[c][1] = k1;
    }
    __syncthreads();

    // flat masked score array (keep already includes validity)
    for (int w = t; w < 3*NPRE; w += 256) {
        int c = w / NPRE, p = w % NPRE;
        int r = rankS[c][p];
        unsigned long long bit = (r < 64) ? (keepBits[c][0] >> r) : (keepBits[c][1] >> (r - 64));
        flatS[w] = (bit & 1ULL) ? clsS[c][p] : -1.0f;
    }
    __syncthreads();

    // stable top-50 over 300 entries, 4-wide; ranks unique
    for (int i = t; i < 3*NPRE; i += 256) {
        float vi = flatS[i];
        int r2 = 0;
        for (int j0 = 0; j0 < 3*NPRE; j0 += 4) {
            float v0 = flatS[j0+0], v1 = flatS[j0+1];
            float v2 = flatS[j0+2], v3 = flatS[j0+3];
            r2 += (int)(v0 > vi || (v0 == vi && (j0+0) < i));
            r2 += (int)(v1 > vi || (v1 == vi && (j0+1) < i));
            r2 += (int)(v2 > vi || (v2 == vi && (j0+2) < i));
            r2 += (int)(v3 > vi || (v3 == vi && (j0+3) < i));
        }
        if (r2 < MAXNUM) {
            int p = i % NPRE;
            int lab = i / NPRE;
            int o = b * MAXNUM + r2;
            float* ob = out + (size_t)o * 7;
            for (int j = 0; j < 7; ++j) ob[j] = bb[p][j];
            out[BATCH*MAXNUM*7 + o] = (float)lab;
            out[BATCH*MAXNUM*8 + o] = vi;
            out[BATCH*MAXNUM*9 + o] = (vi > 0.0f) ? 1.0f : 0.0f;
        }
    }
}

extern "C" void kernel_launch(void* const* d_in, const int* in_sizes, int n_in,
                              void* d_out, int out_size, void* d_ws, size_t ws_size,
                              hipStream_t stream) {
    const float* cls = (const float*)d_in[0];
    const float* box = (const float*)d_in[1];
    const float* dir = (const float*)d_in[2];
    const float* anc = (const float*)d_in[3];
    float* out = (float*)d_out;
    char* ws = (char*)d_ws;

    unsigned* cntB = (unsigned*)(ws + CNTB_OFF);
    unsigned long long* keys = (unsigned long long*)(ws + KEYS_OFF);

    dim3 g(SBLK, BATCH);
    k_score<<<g, 256, 0, stream>>>(cls, cntB, keys);
    k_final<<<BATCH, 256, 0, stream>>>(cls, box, dir, anc, cntB, keys, out);
}